// Round 1
// baseline (197.935 us; speedup 1.0000x reference)
//
#include <hip/hip_runtime.h>
#include <hip/hip_bf16.h>

// Problem: B=2, L=2048, D=1024, N=16  -> rows R = 4096, K = 1024
// y[r,d] = x[r,d] * softplus((x@W1^T)[r,d] + b1[d]) * s[r]
// s[r]   = sum_n (x@W2^T + b2)[r,n] * (x@W3^T + b3)[r,n]
// (dA * h0 == 0, so A is unused.)

#define ROWS 4096
#define KDIM 1024
#define BM 128
#define BN 128
#define BK 32

typedef __attribute__((ext_vector_type(8))) __bf16 bf16x8;
typedef __attribute__((ext_vector_type(4))) float f32x4;

// ---------- helpers ----------
__device__ __forceinline__ unsigned short f2bf_rne(float f) {
    unsigned u = __float_as_uint(f);
    u += 0x7FFFu + ((u >> 16) & 1u);   // round-to-nearest-even
    return (unsigned short)(u >> 16);
}
__device__ __forceinline__ unsigned pack2(float lo, float hi) {
    return (unsigned)f2bf_rne(lo) | ((unsigned)f2bf_rne(hi) << 16);
}
__device__ __forceinline__ void async16(const void* g, void* l) {
    __builtin_amdgcn_global_load_lds(
        (const __attribute__((address_space(1))) void*)g,
        (__attribute__((address_space(3))) void*)l, 16, 0, 0);
}

// ---------- kernel 1: fp32 -> bf16 conversion (x and W1) ----------
// 2560 blocks x 256 thr x 8 elems = 5,242,880 = 4,194,304 (x) + 1,048,576 (W1)
__global__ __launch_bounds__(256) void convert_kernel(
        const float* __restrict__ x, const float* __restrict__ W1,
        unsigned short* __restrict__ xb, unsigned short* __restrict__ w1b) {
    const long long NX = (long long)ROWS * KDIM;        // 4,194,304
    const long long NW1 = (long long)KDIM * KDIM;       // 1,048,576
    long long i = ((long long)blockIdx.x * blockDim.x + threadIdx.x) * 8;
    if (i >= NX + NW1) return;
    const float* src;
    unsigned short* dst;
    if (i < NX) { src = x + i;        dst = xb + i; }
    else        { src = W1 + (i-NX);  dst = w1b + (i-NX); }
    float4 a = *(const float4*)src;
    float4 b = *(const float4*)(src + 4);
    uint4 o;
    o.x = pack2(a.x, a.y); o.y = pack2(a.z, a.w);
    o.z = pack2(b.x, b.y); o.w = pack2(b.z, b.w);
    *(uint4*)dst = o;
}

// ---------- kernel 2: s[r] in fp32 ----------
// 256 blocks x 256 thr. Block handles 16 rows; 16 k-lanes per row (4 floats each).
__global__ __launch_bounds__(256) void s_kernel(
        const float* __restrict__ x,
        const float* __restrict__ W2, const float* __restrict__ b2,
        const float* __restrict__ W3, const float* __restrict__ b3,
        float* __restrict__ s) {
    const int t = threadIdx.x;
    const int r = blockIdx.x * 16 + (t >> 4);
    const int kl = t & 15;
    float accB[16], accC[16];
#pragma unroll
    for (int n = 0; n < 16; ++n) { accB[n] = 0.f; accC[n] = 0.f; }
    const float* xr = x + (size_t)r * KDIM;
    for (int k0 = kl * 4; k0 < KDIM; k0 += 64) {
        float4 xv = *(const float4*)(xr + k0);
#pragma unroll
        for (int n = 0; n < 16; ++n) {
            float4 w2 = *(const float4*)(W2 + (size_t)n * KDIM + k0);
            float4 w3 = *(const float4*)(W3 + (size_t)n * KDIM + k0);
            accB[n] += xv.x*w2.x + xv.y*w2.y + xv.z*w2.z + xv.w*w2.w;
            accC[n] += xv.x*w3.x + xv.y*w3.y + xv.z*w3.z + xv.w*w3.w;
        }
    }
    // butterfly-reduce across the 16 k-lanes (stays inside the wave: groups of 16)
#pragma unroll
    for (int m = 1; m < 16; m <<= 1) {
#pragma unroll
        for (int n = 0; n < 16; ++n) {
            accB[n] += __shfl_xor(accB[n], m, 64);
            accC[n] += __shfl_xor(accC[n], m, 64);
        }
    }
    if (kl == 0) {
        float sv = 0.f;
#pragma unroll
        for (int n = 0; n < 16; ++n)
            sv += (accB[n] + b2[n]) * (accC[n] + b3[n]);
        s[r] = sv;
    }
}

// ---------- kernel 3: bf16 MFMA GEMM + fused epilogue ----------
// grid (8, 32): blockIdx.x = col tile (N=1024), blockIdx.y = row tile (M=4096)
// 256 thr = 4 waves in 2x2; each wave: 64x64 via 4x4 mfma_f32_16x16x32_bf16.
__global__ __launch_bounds__(256) void gemm_fused(
        const unsigned short* __restrict__ xb,   // [4096][1024] bf16
        const unsigned short* __restrict__ w1b,  // [1024][1024] bf16 (row e, col k)
        const float* __restrict__ b1,
        const float* __restrict__ x,             // fp32 original
        const float* __restrict__ s,
        float* __restrict__ y) {
    __shared__ __align__(16) unsigned short As[BM * BK];  // 8 KB, [row][k], no pad
    __shared__ __align__(16) unsigned short Bs[BN * BK];  // 8 KB, [col][k]

    const int t = threadIdx.x;
    const int lane = t & 63;
    const int wv = t >> 6;          // 0..3
    const int wm = wv >> 1;         // wave row 0..1
    const int wn = wv & 1;          // wave col 0..1
    const int row0 = blockIdx.y * BM;
    const int col0 = blockIdx.x * BN;

    f32x4 acc[4][4];
#pragma unroll
    for (int mi = 0; mi < 4; ++mi)
#pragma unroll
        for (int ni = 0; ni < 4; ++ni)
            acc[mi][ni] = (f32x4){0.f, 0.f, 0.f, 0.f};

    const int srow = (lane >> 2);        // 0..15 within chunk
    const int skoff = (lane & 3) * 8;    // 0,8,16,24 elements
    const int ml = lane & 15;
    const int kq = (lane >> 4) * 8;

    for (int k0 = 0; k0 < KDIM; k0 += BK) {
        __syncthreads();
        // stage A and B tiles: each wave stages chunks 2wv, 2wv+1 of each (16 rows/chunk)
#pragma unroll
        for (int i = 0; i < 2; ++i) {
            int c = wv * 2 + i;
            int rrow = c * 16 + srow;
            async16(xb  + (size_t)(row0 + rrow) * KDIM + k0 + skoff, &As[c * 512]);
            async16(w1b + (size_t)(col0 + rrow) * KDIM + k0 + skoff, &Bs[c * 512]);
        }
        __syncthreads();

        bf16x8 af[4], bfr[4];
#pragma unroll
        for (int i = 0; i < 4; ++i) {
            af[i]  = *(const bf16x8*)&As[(wm * 64 + i * 16 + ml) * BK + kq];
            bfr[i] = *(const bf16x8*)&Bs[(wn * 64 + i * 16 + ml) * BK + kq];
        }
#pragma unroll
        for (int mi = 0; mi < 4; ++mi)
#pragma unroll
            for (int ni = 0; ni < 4; ++ni)
                acc[mi][ni] = __builtin_amdgcn_mfma_f32_16x16x32_bf16(
                    af[mi], bfr[ni], acc[mi][ni], 0, 0, 0);
    }

    // epilogue: y = softplus(acc + b1) * x * s  ; D layout: col=lane&15, row=(lane>>4)*4+reg
    const int q4 = (lane >> 4) * 4;
#pragma unroll
    for (int mi = 0; mi < 4; ++mi) {
        const int rbase = row0 + wm * 64 + mi * 16 + q4;
        float4 s4 = *(const float4*)&s[rbase];
        const float* sp4 = (const float*)&s4;
#pragma unroll
        for (int ni = 0; ni < 4; ++ni) {
            const int c = col0 + wn * 64 + ni * 16 + ml;
            const float bias = b1[c];
#pragma unroll
            for (int r = 0; r < 4; ++r) {
                float z = acc[mi][ni][r] + bias;
                float sp = fmaxf(z, 0.f) + log1pf(__expf(-fabsf(z)));
                size_t idx = (size_t)(rbase + r) * KDIM + c;
                y[idx] = sp * x[idx] * sp4[r];
            }
        }
    }
}

// ---------- launch ----------
extern "C" void kernel_launch(void* const* d_in, const int* in_sizes, int n_in,
                              void* d_out, int out_size, void* d_ws, size_t ws_size,
                              hipStream_t stream) {
    const float* x  = (const float*)d_in[0];
    const float* W1 = (const float*)d_in[1];
    const float* b1 = (const float*)d_in[2];
    const float* W2 = (const float*)d_in[3];
    const float* b2 = (const float*)d_in[4];
    const float* W3 = (const float*)d_in[5];
    const float* b3 = (const float*)d_in[6];
    // d_in[7] = A : unused (multiplied by h0 == 0 in the reference)
    float* y = (float*)d_out;

    unsigned short* xb  = (unsigned short*)d_ws;            // 4096*1024 bf16 = 8 MB
    unsigned short* w1b = xb + (size_t)ROWS * KDIM;         // 1024*1024 bf16 = 2 MB
    float* s = (float*)(w1b + (size_t)KDIM * KDIM);         // 4096 f32

    convert_kernel<<<dim3(2560), dim3(256), 0, stream>>>(x, W1, xb, w1b);
    s_kernel<<<dim3(256), dim3(256), 0, stream>>>(x, W2, b2, W3, b3, s);
    gemm_fused<<<dim3(8, 32), dim3(256), 0, stream>>>(xb, w1b, b1, x, s, y);
}

// Round 2
// 148.014 us; speedup vs baseline: 1.3373x; 1.3373x over previous
//
#include <hip/hip_runtime.h>
#include <hip/hip_bf16.h>

// Problem: B=2, L=2048, D=1024, N=16  -> rows R = 4096, K = 1024
// y[r,d] = x[r,d] * softplus((x@W1^T)[r,d] + b1[d]) * s[r]
// s[r]   = sum_n (x@W2^T + b2)[r,n] * (x@W3^T + b3)[r,n]
// (dA * h0 == 0, so A is unused.)

#define ROWS 4096
#define KDIM 1024
#define BM 128
#define BN 128
#define BK 32

typedef __attribute__((ext_vector_type(8))) __bf16 bf16x8;
typedef __attribute__((ext_vector_type(4))) float f32x4;
typedef __attribute__((ext_vector_type(16))) float f32x16;

// ---------- helpers ----------
__device__ __forceinline__ unsigned short f2bf_rne(float f) {
    unsigned u = __float_as_uint(f);
    u += 0x7FFFu + ((u >> 16) & 1u);   // round-to-nearest-even
    return (unsigned short)(u >> 16);
}
__device__ __forceinline__ unsigned pack2(float lo, float hi) {
    return (unsigned)f2bf_rne(lo) | ((unsigned)f2bf_rne(hi) << 16);
}
__device__ __forceinline__ void async16(const void* g, void* l) {
    __builtin_amdgcn_global_load_lds(
        (const __attribute__((address_space(1))) void*)g,
        (__attribute__((address_space(3))) void*)l, 16, 0, 0);
}

// ---------- kernel 1: fp32 -> bf16 conversion (x and W1) ----------
__global__ __launch_bounds__(256) void convert_kernel(
        const float* __restrict__ x, const float* __restrict__ W1,
        unsigned short* __restrict__ xb, unsigned short* __restrict__ w1b) {
    const long long NX = (long long)ROWS * KDIM;        // 4,194,304
    const long long NW1 = (long long)KDIM * KDIM;       // 1,048,576
    long long i = ((long long)blockIdx.x * blockDim.x + threadIdx.x) * 8;
    if (i >= NX + NW1) return;
    const float* src;
    unsigned short* dst;
    if (i < NX) { src = x + i;        dst = xb + i; }
    else        { src = W1 + (i-NX);  dst = w1b + (i-NX); }
    float4 a = *(const float4*)src;
    float4 b = *(const float4*)(src + 4);
    uint4 o;
    o.x = pack2(a.x, a.y); o.y = pack2(a.z, a.w);
    o.z = pack2(b.x, b.y); o.w = pack2(b.z, b.w);
    *(uint4*)dst = o;
}

// ---------- kernel 2: s[r] in fp32 (v2: register accs + 2 rows/wave) ----------
// 512 blocks x 256 thr (4 waves). Each wave: 2 rows (lane>>5 selects row),
// 32 k-lanes per row, 4 floats x 8 slices each. Accumulators are ext_vector
// (guaranteed VGPRs -- v1's float[16] arrays were demoted to scratch: VGPR=36).
__global__ __launch_bounds__(256) void s_kernel(
        const float* __restrict__ x,
        const float* __restrict__ W2, const float* __restrict__ b2,
        const float* __restrict__ W3, const float* __restrict__ b3,
        float* __restrict__ s) {
    const int t = threadIdx.x;
    const int lane = t & 63;
    const int wv = t >> 6;
    const int gw = blockIdx.x * 4 + wv;      // 0..2047
    const int half = lane >> 5;              // which row of the pair
    const int kl = lane & 31;                // k-lane within row
    const int r = gw * 2 + half;

    f32x16 accB = (f32x16)(0.f);
    f32x16 accC = (f32x16)(0.f);
    const float* xr = x + (size_t)r * KDIM;
#pragma unroll
    for (int i = 0; i < 8; ++i) {
        const int k = kl * 4 + i * 128;
        float4 xv = *(const float4*)(xr + k);
#pragma unroll
        for (int n = 0; n < 16; ++n) {
            float4 w2 = *(const float4*)(W2 + (size_t)n * KDIM + k);
            float4 w3 = *(const float4*)(W3 + (size_t)n * KDIM + k);
            accB[n] += xv.x*w2.x + xv.y*w2.y + xv.z*w2.z + xv.w*w2.w;
            accC[n] += xv.x*w3.x + xv.y*w3.y + xv.z*w3.z + xv.w*w3.w;
        }
    }
    // butterfly across the 32 k-lanes; XOR masks <32 never cross the half split
#pragma unroll
    for (int m = 1; m < 32; m <<= 1) {
#pragma unroll
        for (int n = 0; n < 16; ++n) {
            accB[n] += __shfl_xor(accB[n], m, 64);
            accC[n] += __shfl_xor(accC[n], m, 64);
        }
    }
    if (kl == 0) {
        float sv = 0.f;
#pragma unroll
        for (int n = 0; n < 16; ++n)
            sv += (accB[n] + b2[n]) * (accC[n] + b3[n]);
        s[r] = sv;
    }
}

// ---------- kernel 3: bf16 MFMA GEMM + fused epilogue (unchanged) ----------
__global__ __launch_bounds__(256) void gemm_fused(
        const unsigned short* __restrict__ xb,   // [4096][1024] bf16
        const unsigned short* __restrict__ w1b,  // [1024][1024] bf16 (row e, col k)
        const float* __restrict__ b1,
        const float* __restrict__ x,             // fp32 original
        const float* __restrict__ s,
        float* __restrict__ y) {
    __shared__ __align__(16) unsigned short As[BM * BK];  // 8 KB, [row][k], no pad
    __shared__ __align__(16) unsigned short Bs[BN * BK];  // 8 KB, [col][k]

    const int t = threadIdx.x;
    const int lane = t & 63;
    const int wv = t >> 6;          // 0..3
    const int wm = wv >> 1;         // wave row 0..1
    const int wn = wv & 1;          // wave col 0..1
    const int row0 = blockIdx.y * BM;
    const int col0 = blockIdx.x * BN;

    f32x4 acc[4][4];
#pragma unroll
    for (int mi = 0; mi < 4; ++mi)
#pragma unroll
        for (int ni = 0; ni < 4; ++ni)
            acc[mi][ni] = (f32x4){0.f, 0.f, 0.f, 0.f};

    const int srow = (lane >> 2);        // 0..15 within chunk
    const int skoff = (lane & 3) * 8;    // 0,8,16,24 elements
    const int ml = lane & 15;
    const int kq = (lane >> 4) * 8;

    for (int k0 = 0; k0 < KDIM; k0 += BK) {
        __syncthreads();
#pragma unroll
        for (int i = 0; i < 2; ++i) {
            int c = wv * 2 + i;
            int rrow = c * 16 + srow;
            async16(xb  + (size_t)(row0 + rrow) * KDIM + k0 + skoff, &As[c * 512]);
            async16(w1b + (size_t)(col0 + rrow) * KDIM + k0 + skoff, &Bs[c * 512]);
        }
        __syncthreads();

        bf16x8 af[4], bfr[4];
#pragma unroll
        for (int i = 0; i < 4; ++i) {
            af[i]  = *(const bf16x8*)&As[(wm * 64 + i * 16 + ml) * BK + kq];
            bfr[i] = *(const bf16x8*)&Bs[(wn * 64 + i * 16 + ml) * BK + kq];
        }
#pragma unroll
        for (int mi = 0; mi < 4; ++mi)
#pragma unroll
            for (int ni = 0; ni < 4; ++ni)
                acc[mi][ni] = __builtin_amdgcn_mfma_f32_16x16x32_bf16(
                    af[mi], bfr[ni], acc[mi][ni], 0, 0, 0);
    }

    // epilogue: y = softplus(acc + b1) * x * s ; D layout: col=lane&15, row=(lane>>4)*4+reg
    const int q4 = (lane >> 4) * 4;
#pragma unroll
    for (int mi = 0; mi < 4; ++mi) {
        const int rbase = row0 + wm * 64 + mi * 16 + q4;
        float4 s4 = *(const float4*)&s[rbase];
        const float* sp4 = (const float*)&s4;
#pragma unroll
        for (int ni = 0; ni < 4; ++ni) {
            const int c = col0 + wn * 64 + ni * 16 + ml;
            const float bias = b1[c];
#pragma unroll
            for (int r = 0; r < 4; ++r) {
                float z = acc[mi][ni][r] + bias;
                float sp = fmaxf(z, 0.f) + log1pf(__expf(-fabsf(z)));
                size_t idx = (size_t)(rbase + r) * KDIM + c;
                y[idx] = sp * x[idx] * sp4[r];
            }
        }
    }
}

// ---------- launch ----------
extern "C" void kernel_launch(void* const* d_in, const int* in_sizes, int n_in,
                              void* d_out, int out_size, void* d_ws, size_t ws_size,
                              hipStream_t stream) {
    const float* x  = (const float*)d_in[0];
    const float* W1 = (const float*)d_in[1];
    const float* b1 = (const float*)d_in[2];
    const float* W2 = (const float*)d_in[3];
    const float* b2 = (const float*)d_in[4];
    const float* W3 = (const float*)d_in[5];
    const float* b3 = (const float*)d_in[6];
    // d_in[7] = A : unused (multiplied by h0 == 0 in the reference)
    float* y = (float*)d_out;

    unsigned short* xb  = (unsigned short*)d_ws;            // 4096*1024 bf16 = 8 MB
    unsigned short* w1b = xb + (size_t)ROWS * KDIM;         // 1024*1024 bf16 = 2 MB
    float* s = (float*)(w1b + (size_t)KDIM * KDIM);         // 4096 f32

    convert_kernel<<<dim3(2560), dim3(256), 0, stream>>>(x, W1, xb, w1b);
    s_kernel<<<dim3(512), dim3(256), 0, stream>>>(x, W2, b2, W3, b3, s);
    gemm_fused<<<dim3(8, 32), dim3(256), 0, stream>>>(xb, w1b, b1, x, s, y);
}

// Round 3
// 141.907 us; speedup vs baseline: 1.3948x; 1.0430x over previous
//
#include <hip/hip_runtime.h>
#include <hip/hip_bf16.h>

// Problem: B=2, L=2048, D=1024, N=16  -> rows R = 4096, K = 1024
// y[r,d] = x[r,d] * softplus((x@W1^T)[r,d] + b1[d]) * s[r]
// s[r]   = sum_n (x@W2^T + b2)[r,n] * (x@W3^T + b3)[r,n]
// (dA * h0 == 0, so A is unused.)

#define ROWS 4096
#define KDIM 1024
// GEMM tile: 128x64, BK=32 -> grid (16,32)=512 blocks (2+/CU for overlap)
#define BM 128
#define BN 64
#define BK 32

typedef __attribute__((ext_vector_type(8))) __bf16 bf16x8;
typedef __attribute__((ext_vector_type(4))) float f32x4;
typedef __attribute__((ext_vector_type(16))) float f32x16;

// ---------- helpers ----------
__device__ __forceinline__ unsigned short f2bf_rne(float f) {
    unsigned u = __float_as_uint(f);
    u += 0x7FFFu + ((u >> 16) & 1u);   // round-to-nearest-even
    return (unsigned short)(u >> 16);
}
__device__ __forceinline__ unsigned pack2(float lo, float hi) {
    return (unsigned)f2bf_rne(lo) | ((unsigned)f2bf_rne(hi) << 16);
}
__device__ __forceinline__ void async16(const void* g, void* l) {
    __builtin_amdgcn_global_load_lds(
        (const __attribute__((address_space(1))) void*)g,
        (__attribute__((address_space(3))) void*)l, 16, 0, 0);
}

// ---------- kernel 1: fused x->bf16 convert + s[r]  (+ W1 convert in tail blocks) ----------
// blocks [0,512): 8 rows each -- 4 waves x 2 rows; 32 k-lanes/row; converts x to xb
//                 while accumulating the rank-16 bilinear form s[r].
// blocks [512,1024): W1 fp32 -> bf16, 8 elems/thread.
__global__ __launch_bounds__(256) void prep_kernel(
        const float* __restrict__ x,  const float* __restrict__ W1,
        const float* __restrict__ W2, const float* __restrict__ b2,
        const float* __restrict__ W3, const float* __restrict__ b3,
        unsigned short* __restrict__ xb, unsigned short* __restrict__ w1b,
        float* __restrict__ s) {
    if (blockIdx.x >= 512) {
        long long i = (((long long)blockIdx.x - 512) * 256 + threadIdx.x) * 8;
        float4 a = *(const float4*)(W1 + i);
        float4 b = *(const float4*)(W1 + i + 4);
        uint4 o;
        o.x = pack2(a.x, a.y); o.y = pack2(a.z, a.w);
        o.z = pack2(b.x, b.y); o.w = pack2(b.z, b.w);
        *(uint4*)(w1b + i) = o;
        return;
    }
    const int t = threadIdx.x;
    const int lane = t & 63;
    const int wv = t >> 6;
    const int half = lane >> 5;              // which row of the wave's pair
    const int kl = lane & 31;                // k-lane within row
    const int r = blockIdx.x * 8 + wv * 2 + half;

    f32x16 accB = (f32x16)(0.f);
    f32x16 accC = (f32x16)(0.f);
    const float* xr = x + (size_t)r * KDIM;
    unsigned short* xbr = xb + (size_t)r * KDIM;
#pragma unroll
    for (int i = 0; i < 8; ++i) {
        const int k = kl * 4 + i * 128;
        float4 xv = *(const float4*)(xr + k);
        uint2 o2;                            // convert this slice to bf16 on the way
        o2.x = pack2(xv.x, xv.y);
        o2.y = pack2(xv.z, xv.w);
        *(uint2*)(xbr + k) = o2;
#pragma unroll
        for (int n = 0; n < 16; ++n) {
            float4 w2 = *(const float4*)(W2 + (size_t)n * KDIM + k);
            float4 w3 = *(const float4*)(W3 + (size_t)n * KDIM + k);
            accB[n] += xv.x*w2.x + xv.y*w2.y + xv.z*w2.z + xv.w*w2.w;
            accC[n] += xv.x*w3.x + xv.y*w3.y + xv.z*w3.z + xv.w*w3.w;
        }
    }
    // butterfly across the 32 k-lanes; XOR masks <32 never cross the half split
#pragma unroll
    for (int m = 1; m < 32; m <<= 1) {
#pragma unroll
        for (int n = 0; n < 16; ++n) {
            accB[n] += __shfl_xor(accB[n], m, 64);
            accC[n] += __shfl_xor(accC[n], m, 64);
        }
    }
    if (kl == 0) {
        float sv = 0.f;
#pragma unroll
        for (int n = 0; n < 16; ++n)
            sv += (accB[n] + b2[n]) * (accC[n] + b3[n]);
        s[r] = sv;
    }
}

// ---------- kernel 2: bf16 MFMA GEMM + fused epilogue ----------
// grid (16, 32): blockIdx.x = col tile (N=1024 / 64), blockIdx.y = row tile (M=4096 / 128)
// 256 thr = 4 waves in 2x2; each wave: 64x32 via 4x2 mfma_f32_16x16x32_bf16.
__global__ __launch_bounds__(256) void gemm_fused(
        const unsigned short* __restrict__ xb,   // [4096][1024] bf16
        const unsigned short* __restrict__ w1b,  // [1024][1024] bf16 (row e, col k)
        const float* __restrict__ b1,
        const float* __restrict__ x,             // fp32 original
        const float* __restrict__ s,
        float* __restrict__ y) {
    __shared__ __align__(16) unsigned short As[BM * BK];  // 8 KB, [row][k]
    __shared__ __align__(16) unsigned short Bs[BN * BK];  // 4 KB, [col][k]

    const int t = threadIdx.x;
    const int lane = t & 63;
    const int wv = t >> 6;          // 0..3
    const int wm = wv >> 1;         // wave row 0..1 (64 rows each)
    const int wn = wv & 1;          // wave col 0..1 (32 cols each)
    const int row0 = blockIdx.y * BM;
    const int col0 = blockIdx.x * BN;

    f32x4 acc[4][2];
#pragma unroll
    for (int mi = 0; mi < 4; ++mi)
#pragma unroll
        for (int ni = 0; ni < 2; ++ni)
            acc[mi][ni] = (f32x4){0.f, 0.f, 0.f, 0.f};

    const int srow = (lane >> 2);        // 0..15 within 16-row chunk
    const int skoff = (lane & 3) * 8;    // 0,8,16,24 elements
    const int ml = lane & 15;
    const int kq = (lane >> 4) * 8;

    for (int k0 = 0; k0 < KDIM; k0 += BK) {
        __syncthreads();
        // A: 8 chunks of 16 rows; wave wv stages chunks 2wv, 2wv+1
#pragma unroll
        for (int i = 0; i < 2; ++i) {
            int c = wv * 2 + i;
            int rrow = c * 16 + srow;
            async16(xb + (size_t)(row0 + rrow) * KDIM + k0 + skoff, &As[c * 512]);
        }
        // B: 4 chunks of 16 rows; wave wv stages chunk wv
        {
            int rrow = wv * 16 + srow;
            async16(w1b + (size_t)(col0 + rrow) * KDIM + k0 + skoff, &Bs[wv * 512]);
        }
        __syncthreads();

        bf16x8 af[4], bfr[2];
#pragma unroll
        for (int i = 0; i < 4; ++i)
            af[i]  = *(const bf16x8*)&As[(wm * 64 + i * 16 + ml) * BK + kq];
#pragma unroll
        for (int i = 0; i < 2; ++i)
            bfr[i] = *(const bf16x8*)&Bs[(wn * 32 + i * 16 + ml) * BK + kq];
#pragma unroll
        for (int mi = 0; mi < 4; ++mi)
#pragma unroll
            for (int ni = 0; ni < 2; ++ni)
                acc[mi][ni] = __builtin_amdgcn_mfma_f32_16x16x32_bf16(
                    af[mi], bfr[ni], acc[mi][ni], 0, 0, 0);
    }

    // epilogue: y = softplus(acc + b1) * x * s ; D layout: col=lane&15, row=(lane>>4)*4+reg
    const int q4 = (lane >> 4) * 4;
#pragma unroll
    for (int mi = 0; mi < 4; ++mi) {
        const int rbase = row0 + wm * 64 + mi * 16 + q4;
        float4 s4 = *(const float4*)&s[rbase];
        const float* sp4 = (const float*)&s4;
#pragma unroll
        for (int ni = 0; ni < 2; ++ni) {
            const int c = col0 + wn * 32 + ni * 16 + ml;
            const float bias = b1[c];
#pragma unroll
            for (int r = 0; r < 4; ++r) {
                float z = acc[mi][ni][r] + bias;
                float sp = fmaxf(z, 0.f) + log1pf(__expf(-fabsf(z)));
                size_t idx = (size_t)(rbase + r) * KDIM + c;
                y[idx] = sp * x[idx] * sp4[r];
            }
        }
    }
}

// ---------- launch ----------
extern "C" void kernel_launch(void* const* d_in, const int* in_sizes, int n_in,
                              void* d_out, int out_size, void* d_ws, size_t ws_size,
                              hipStream_t stream) {
    const float* x  = (const float*)d_in[0];
    const float* W1 = (const float*)d_in[1];
    const float* b1 = (const float*)d_in[2];
    const float* W2 = (const float*)d_in[3];
    const float* b2 = (const float*)d_in[4];
    const float* W3 = (const float*)d_in[5];
    const float* b3 = (const float*)d_in[6];
    // d_in[7] = A : unused (multiplied by h0 == 0 in the reference)
    float* y = (float*)d_out;

    unsigned short* xb  = (unsigned short*)d_ws;            // 4096*1024 bf16 = 8 MB
    unsigned short* w1b = xb + (size_t)ROWS * KDIM;         // 1024*1024 bf16 = 2 MB
    float* s = (float*)(w1b + (size_t)KDIM * KDIM);         // 4096 f32

    prep_kernel<<<dim3(1024), dim3(256), 0, stream>>>(x, W1, W2, b2, W3, b3, xb, w1b, s);
    gemm_fused<<<dim3(16, 32), dim3(256), 0, stream>>>(xb, w1b, b1, x, s, y);
}